// Round 4
// baseline (244.902 us; speedup 1.0000x reference)
//
#include <hip/hip_runtime.h>
#include <hip/hip_fp16.h>
#include <math.h>
#include <stdint.h>

#define A_ANG 400
#define DDET  512
#define NVOL  256
#define CCH   32
#define KSZ   11
#define PI_F  3.14159265358979323846f

#define NCHUNK 2
#define APC (A_ANG / NCHUNK)   // 200 angles per block
#define RING 8                 // LDS ring slots (2 KB each, f16)
#define PD   6                 // prefetch distance in angles (2 gll4 per angle)

typedef _Float16 half8 __attribute__((ext_vector_type(8)));
typedef float   floatx4 __attribute__((ext_vector_type(4)));

typedef __attribute__((address_space(3))) uint32_t       lds_u32;
typedef const __attribute__((address_space(1))) uint32_t glb_u32;
#define GLL4(gp, lp) \
  __builtin_amdgcn_global_load_lds((glb_u32*)(gp), (lds_u32*)(lp), 4, 0, 0)

// ---------------------------------------------------------------------------
// K1: causal detector conv -> f16 CHANNEL-MAJOR y[a][c][d] (packed half2).
// Each thread computes 2 adjacent d's and stores one u32.
// ---------------------------------------------------------------------------
__global__ __launch_bounds__(256) void k_detconv(const float* __restrict__ x,
                                                 const float* __restrict__ wdet,
                                                 const float* __restrict__ bdet,
                                                 __half* __restrict__ y2h) {
  __shared__ float wl[CCH * KSZ];
  __shared__ float bl[CCH];
  int t = threadIdx.x;
  for (int e = t; e < CCH * KSZ; e += 256) wl[e] = wdet[e];
  if (t < CCH) bl[t] = bdet[t];
  __syncthreads();

  int idx = blockIdx.x * 256 + t;  // = a*8192 + c*256 + d2
  int d2 = idx & 255;
  int c = (idx >> 8) & 31;
  int a = idx >> 13;
  const float* xr = x + a * DDET;
  int d0 = 2 * d2;
  float acc0 = bl[c], acc1 = bl[c];
#pragma unroll
  for (int k = 0; k < KSZ; ++k) {
    float wv = wl[c * KSZ + k];
    int dd0 = d0 + k - (KSZ - 1);
    int dd1 = dd0 + 1;
    float xv0 = (dd0 >= 0) ? xr[dd0] : 0.0f;
    float xv1 = (dd1 >= 0) ? xr[dd1] : 0.0f;
    acc0 = fmaf(wv, xv0, acc0);
    acc1 = fmaf(wv, xv1, acc1);
  }
  __half2 hv = __floats2half2_rn(acc0, acc1);
  *reinterpret_cast<__half2*>(y2h + ((size_t)(a * CCH + c) * DDET + d0)) = hv;
}

// ---------------------------------------------------------------------------
// K2: backprojection v5 — MFMA formulation.
// Per angle, per 16-px image row: vol[px 16][ch 32] += W[16][32] * g[32][32]
// with W the 2-nnz linear-interp hat built in registers (f16), g staged f16.
//   - A/B use the SAME k<->(lane>>4, slot) convention (k = 8h + j), so the
//     contraction is invariant to the HW's true k decomposition; row/col
//     mappings are the m89-verified ones (A row / B,D col = lane&15,
//     D row = 4*(lane>>4)+reg).
//   - staging: 2x gll4 per wave per angle; LDS u32 entry (c,kp) = ch c,
//     cell pair (2kp,2kp+1) rel. to EVEN base; B-frag = 1 ds_read_b128.
//   - ring 8 x 2KB, PD=6 angles (12 glls/wave in flight), vmcnt(8) =
//     2 oldest angles landed; one barrier per 2 angles.
//   - epilogue unchanged: LDS transpose + line-coalesced atomics.
// Window: base = (floor(uc)-16)&~1 in [56,420]; e = k0-base in [4,29] ->
// e+1 <= 30 < 32 (clamped 0..30 for safety).
// ---------------------------------------------------------------------------
__global__ __launch_bounds__(256) void k_backproj(const __half* __restrict__ y2h,
                                                  float* __restrict__ vol) {
  __shared__ __align__(16) float s_mem[8448];  // ring 16KB | epilogue 32x257
  __shared__ float s_sin[APC];
  __shared__ float s_cos[APC];

  int t = threadIdx.x;
  int lane = t & 63;
  int w = t >> 6;        // wave id 0..3
  int h = lane >> 4;     // k-group 0..3
  int r = lane & 15;     // A-row / B-col / D-col index

  int tile = blockIdx.x & 255;
  int chunk = blockIdx.x >> 8;
  int a0 = chunk * APC;

  for (int a = t; a < APC; a += 256) {
    float ph = ((float)(a0 + a) + 0.5f) * (PI_F / (float)A_ANG);
    float sv, cv;
    sincosf(ph, &sv, &cv);
    s_sin[a] = sv;
    s_cos[a] = cv;
  }

  int bi = tile >> 4, bj = tile & 15;
  float Xc = 120.0f - (float)(bi * 16);          // tile-center coords
  float Yc = (float)(bj * 16) - 120.0f;
  float Xw = 127.5f - (float)(bi * 16 + 4 * w);  // this wave's first row
  float Ypr = (float)(bj * 16 + r) - 127.5f;     // this lane's column

  // staging constants: entry e = w*128 + i*64 + lane -> (c = e>>4, kp = e&15)
  int e0 = w * 128 + lane;
  int cst0 = (e0 >> 4) * 256 + (e0 & 15);
  int e1 = e0 + 64;
  int cst1 = (e1 >> 4) * 256 + (e1 & 15);

  const uint32_t* y2u = (const uint32_t*)y2h;  // [a][c][256 cell-pairs]
  uint32_t* ring = (uint32_t*)s_mem;

  floatx4 acc[4][2];
#pragma unroll
  for (int m = 0; m < 4; ++m)
#pragma unroll
    for (int n = 0; n < 2; ++n) acc[m][n] = (floatx4){0.f, 0.f, 0.f, 0.f};

  __syncthreads();  // tables ready (no loads in flight yet)

  auto issue = [&](int an, int slot) {
    float sp = s_sin[an], cp = s_cos[an];
    int ib = ((int)floorf(fmaf(Xc, sp, fmaf(Yc, cp, 255.5f))) - 16) & ~1;
    const uint32_t* src = y2u + (size_t)(a0 + an) * 8192 + (ib >> 1);
    uint32_t* lb = ring + slot * 512 + w * 128;
    GLL4(src + cst0, lb);
    GLL4(src + cst1, lb + 64);
  };

  auto compute = [&](int k) {
    float sp = s_sin[k], cp = s_cos[k];
    float uc = fmaf(Xc, sp, fmaf(Yc, cp, 255.5f));
    int ibase = ((int)floorf(uc) - 16) & ~1;
    const uint32_t* rb = ring + (k & (RING - 1)) * 512;
    half8 bf0 = *(const half8*)(rb + r * 16 + 4 * h);          // ch 0..15
    half8 bf1 = *(const half8*)(rb + (16 + r) * 16 + 4 * h);   // ch 16..31
    float yc = fmaf(Ypr, cp, 255.5f);
    float um = fmaf(Xw, sp, yc);
#pragma unroll
    for (int m = 0; m < 4; ++m) {
      float k0f = floorf(um);
      float wf = um - k0f;
      int e = (int)k0f - ibase;
      e = min(30, max(0, e));  // provably [4,29]
      float w0 = 1.0f - wf;
      uint32_t hw0 = (uint32_t)__half_as_ushort(__float2half_rn(w0));
      uint32_t hw1 = (uint32_t)__half_as_ushort(__float2half_rn(wf));
      uint32_t P01 = hw0 | (hw1 << 16);  // (w0, w1)
      uint32_t P0w = hw0 << 16;          // (0, w0)
      uint32_t PA = hw1;                 // (w1, 0)
      int d0 = e - 8 * h;
      union {
        uint32_t u[4];
        half8 v;
      } af;
#pragma unroll
      for (int j2 = 0; j2 < 4; ++j2) {
        uint32_t rj = (d0 == 2 * j2) ? P01 : 0u;
        rj = (d0 == 2 * j2 + 1) ? P0w : rj;
        rj = (d0 == 2 * j2 - 1) ? PA : rj;
        af.u[j2] = rj;
      }
      acc[m][0] =
          __builtin_amdgcn_mfma_f32_16x16x32_f16(af.v, bf0, acc[m][0], 0, 0, 0);
      acc[m][1] =
          __builtin_amdgcn_mfma_f32_16x16x32_f16(af.v, bf1, acc[m][1], 0, 0, 0);
      um -= sp;  // next image row: u -= sin
    }
  };

  // prologue: fill pipeline with angles 0..PD-1 (12 glls per wave)
#pragma unroll
  for (int p = 0; p < PD; ++p) issue(p, p & (RING - 1));
  asm volatile("s_waitcnt vmcnt(8)" ::: "memory");  // angles 0,1 landed
  __builtin_amdgcn_s_barrier();

  for (int k = 0; k < APC; k += 2) {
    compute(k);
    compute(k + 1);
    int a1 = k + PD;     a1 = (a1 < APC) ? a1 : (APC - 1);
    int a2 = k + PD + 1; a2 = (a2 < APC) ? a2 : (APC - 1);
    issue(a1, (k + PD) & (RING - 1));
    issue(a2, (k + PD + 1) & (RING - 1));
    asm volatile("s_waitcnt vmcnt(8)" ::: "memory");  // k+2, k+3 landed
    __builtin_amdgcn_s_barrier();
  }

  // drain before reusing s_mem (tail glls still target ring slots)
  asm volatile("s_waitcnt vmcnt(0)" ::: "memory");
  __syncthreads();

  // epilogue: D layout (m89): lane holds rows 4h+jr, col r per tile.
  const float DPHI = PI_F / (float)A_ANG;
#pragma unroll
  for (int m = 0; m < 4; ++m)
#pragma unroll
    for (int n = 0; n < 2; ++n)
#pragma unroll
      for (int jr = 0; jr < 4; ++jr) {
        int ch = 16 * n + r;
        int px = (4 * w + m) * 16 + 4 * h + jr;  // (i-local)*16 + j-local
        s_mem[ch * 257 + px] = acc[m][n][jr] * DPHI;
      }
  __syncthreads();

  size_t gbase = ((size_t)(bi * 16) * NVOL + (size_t)(bj * 16)) * CCH;
#pragma unroll
  for (int m = 0; m < 32; ++m) {
    int f = m * 256 + t;
    int c = f & 31;
    int p2 = f >> 5;  // pixel 0..255
    int jj = p2 & 15, ii = p2 >> 4;
    float v = s_mem[c * 257 + p2];
    atomicAdd(vol + gbase + ((size_t)ii * NVOL + jj) * CCH + c, v);
  }
}

// ---------------------------------------------------------------------------
// K3: 3x3 causal conv 32->32 + sigmoid.  in/out channel-last [i][j][32].
// ---------------------------------------------------------------------------
__global__ __launch_bounds__(256) void k_conv1(const float* __restrict__ vol,
                                               const float* __restrict__ w1,
                                               const float* __restrict__ b1,
                                               float* __restrict__ out1) {
  __shared__ float wl[9 * CCH * CCH];  // 36 KB: [p][ci][o]
  int t = threadIdx.x;
  for (int e = t; e < 9 * CCH * CCH; e += 256) {
    int o = e & 31;
    int ci = (e >> 5) & 31;
    int p = e >> 10;           // 0..8
    int di = p / 3, dj = p % 3;
    wl[e] = w1[((o * CCH + ci) * 3 + di) * 3 + dj];
  }
  __syncthreads();

  int pix = blockIdx.x * 256 + t;
  int j = pix & 255, i = pix >> 8;

  float acc[CCH];
#pragma unroll
  for (int o = 0; o < CCH; ++o) acc[o] = b1[o];

#pragma unroll 1
  for (int p = 0; p < 9; ++p) {
    int di = p / 3, dj = p % 3;
    int ii = i + di - 2, jj = j + dj - 2;
    if (ii < 0 || jj < 0) continue;   // zero-padded region contributes nothing
    const float4* ip4 = (const float4*)(vol + ((size_t)(ii * NVOL + jj)) * CCH);
    const float* wp = &wl[p * CCH * CCH];
#pragma unroll
    for (int q = 0; q < 8; ++q) {
      float4 v = ip4[q];
      float iv[4] = {v.x, v.y, v.z, v.w};
#pragma unroll
      for (int cc = 0; cc < 4; ++cc) {
        const float4* wv4 = (const float4*)(wp + (4 * q + cc) * CCH);
#pragma unroll
        for (int o4 = 0; o4 < 8; ++o4) {
          float4 wv = wv4[o4];
          acc[o4 * 4 + 0] = fmaf(iv[cc], wv.x, acc[o4 * 4 + 0]);
          acc[o4 * 4 + 1] = fmaf(iv[cc], wv.y, acc[o4 * 4 + 1]);
          acc[o4 * 4 + 2] = fmaf(iv[cc], wv.z, acc[o4 * 4 + 2]);
          acc[o4 * 4 + 3] = fmaf(iv[cc], wv.w, acc[o4 * 4 + 3]);
        }
      }
    }
  }

  float4* op = (float4*)(out1 + (size_t)pix * CCH);
#pragma unroll
  for (int o4 = 0; o4 < 8; ++o4) {
    float4 v;
    v.x = 1.0f / (1.0f + expf(-acc[o4 * 4 + 0]));
    v.y = 1.0f / (1.0f + expf(-acc[o4 * 4 + 1]));
    v.z = 1.0f / (1.0f + expf(-acc[o4 * 4 + 2]));
    v.w = 1.0f / (1.0f + expf(-acc[o4 * 4 + 3]));
    op[o4] = v;
  }
}

// ---------------------------------------------------------------------------
// K4: 3x3 causal conv 32->1 + sigmoid.  out[i][j] row-major (matches ref).
// ---------------------------------------------------------------------------
__global__ __launch_bounds__(256) void k_conv2(const float* __restrict__ s1,
                                               const float* __restrict__ w2,
                                               const float* __restrict__ b2,
                                               float* __restrict__ out) {
  __shared__ float wl[9 * CCH];  // [p][ci]
  int t = threadIdx.x;
  for (int e = t; e < 9 * CCH; e += 256) {
    int ci = e & 31, p = e >> 5;
    int di = p / 3, dj = p % 3;
    wl[e] = w2[ci * 9 + di * 3 + dj];
  }
  __syncthreads();

  int pix = blockIdx.x * 256 + t;
  int j = pix & 255, i = pix >> 8;

  float acc = b2[0];
#pragma unroll 1
  for (int p = 0; p < 9; ++p) {
    int di = p / 3, dj = p % 3;
    int ii = i + di - 2, jj = j + dj - 2;
    if (ii < 0 || jj < 0) continue;
    const float4* ip4 = (const float4*)(s1 + ((size_t)(ii * NVOL + jj)) * CCH);
    const float4* wv4 = (const float4*)(&wl[p * CCH]);
#pragma unroll
    for (int q = 0; q < 8; ++q) {
      float4 v = ip4[q];
      float4 wv = wv4[q];
      acc = fmaf(v.x, wv.x, acc);
      acc = fmaf(v.y, wv.y, acc);
      acc = fmaf(v.z, wv.z, acc);
      acc = fmaf(v.w, wv.w, acc);
    }
  }
  out[pix] = 1.0f / (1.0f + expf(-acc));
}

// ---------------------------------------------------------------------------
extern "C" void kernel_launch(void* const* d_in, const int* in_sizes, int n_in,
                              void* d_out, int out_size, void* d_ws,
                              size_t ws_size, hipStream_t stream) {
  const float* x    = (const float*)d_in[0];  // [1,1,400,512]
  const float* wdet = (const float*)d_in[1];  // [32,1,1,11]
  const float* bdet = (const float*)d_in[2];  // [32]
  const float* w1   = (const float*)d_in[3];  // [32,32,3,3]
  const float* b1   = (const float*)d_in[4];  // [32]
  const float* w2   = (const float*)d_in[5];  // [1,32,3,3]
  const float* b2   = (const float*)d_in[6];  // [1]
  float* out = (float*)d_out;                 // [1,1,256,256]

  float* ws = (float*)d_ws;
  __half* y2h = (__half*)ws;                         // [400][32][512] f16 = 13.1 MB
  float* vol  = ws + (A_ANG * CCH * DDET) / 2;       // [256][256][32] f32 = 8.4 MB
  float* sig1 = vol + NVOL * NVOL * CCH;             // [256][256][32] f32 = 8.4 MB

  k_detconv<<<dim3((A_ANG * CCH * DDET / 2) / 256), dim3(256), 0, stream>>>(
      x, wdet, bdet, y2h);
  // vol accumulated by 2 chunk-blocks per tile via line-coalesced atomics
  hipMemsetAsync(vol, 0, (size_t)NVOL * NVOL * CCH * sizeof(float), stream);
  k_backproj<<<dim3(256 * NCHUNK), dim3(256), 0, stream>>>(y2h, vol);
  k_conv1<<<dim3(256), dim3(256), 0, stream>>>(vol, w1, b1, sig1);
  k_conv2<<<dim3(256), dim3(256), 0, stream>>>(sig1, w2, b2, out);
}

// Round 6
// 223.203 us; speedup vs baseline: 1.0972x; 1.0972x over previous
//
#include <hip/hip_runtime.h>
#include <hip/hip_fp16.h>
#include <math.h>
#include <stdint.h>

#define A_ANG 400
#define DDET  512
#define NVOL  256
#define CCH   32
#define KSZ   11
#define PI_F  3.14159265358979323846f

#define NCHUNK 8
#define APC (A_ANG / NCHUNK)   // 50 angles per block
#define RING 8                 // LDS ring slots (2 KB each, f16)
#define PD   6                 // prefetch distance in angles (2 gll4 per angle)

typedef _Float16 half8 __attribute__((ext_vector_type(8)));
typedef __fp16  fp16x2 __attribute__((ext_vector_type(2)));  // cvt_pkrtz ret type
typedef float   floatx4 __attribute__((ext_vector_type(4)));

typedef __attribute__((address_space(3))) uint32_t       lds_u32;
typedef const __attribute__((address_space(1))) uint32_t glb_u32;
#define GLL4(gp, lp) \
  __builtin_amdgcn_global_load_lds((glb_u32*)(gp), (lds_u32*)(lp), 4, 0, 0)

// ---------------------------------------------------------------------------
// K1: causal detector conv -> f16 CHANNEL-MAJOR y[a][c][d] (packed half2).
// ---------------------------------------------------------------------------
__global__ __launch_bounds__(256) void k_detconv(const float* __restrict__ x,
                                                 const float* __restrict__ wdet,
                                                 const float* __restrict__ bdet,
                                                 __half* __restrict__ y2h) {
  __shared__ float wl[CCH * KSZ];
  __shared__ float bl[CCH];
  int t = threadIdx.x;
  for (int e = t; e < CCH * KSZ; e += 256) wl[e] = wdet[e];
  if (t < CCH) bl[t] = bdet[t];
  __syncthreads();

  int idx = blockIdx.x * 256 + t;  // = a*8192 + c*256 + d2
  int d2 = idx & 255;
  int c = (idx >> 8) & 31;
  int a = idx >> 13;
  const float* xr = x + a * DDET;
  int d0 = 2 * d2;
  float acc0 = bl[c], acc1 = bl[c];
#pragma unroll
  for (int k = 0; k < KSZ; ++k) {
    float wv = wl[c * KSZ + k];
    int dd0 = d0 + k - (KSZ - 1);
    int dd1 = dd0 + 1;
    float xv0 = (dd0 >= 0) ? xr[dd0] : 0.0f;
    float xv1 = (dd1 >= 0) ? xr[dd1] : 0.0f;
    acc0 = fmaf(wv, xv0, acc0);
    acc1 = fmaf(wv, xv1, acc1);
  }
  __half2 hv = __floats2half2_rn(acc0, acc1);
  *reinterpret_cast<__half2*>(y2h + ((size_t)(a * CCH + c) * DDET + d0)) = hv;
}

// ---------------------------------------------------------------------------
// K2: backprojection v6 — MFMA + full occupancy + cheaper A-build.
//   - NCHUNK=8 -> 2048 blocks = 8 blocks/CU (32 waves/CU).  Enabled by
//     slimming LDS to ~17 KB: epilogue transposes 16 channels per pass
//     (2 passes) instead of all 32.
//   - A-build: v_cvt_pkrtz packs (1 instr per half2 pattern) + 2-compare
//     select (lo/hi folded from even/odd by one cndmask pair).
//   - pipeline unchanged from v5: ring 8 x 2KB, PD=6, vmcnt(8), one
//     barrier per 2 angles; staging 2x gll4 per wave per angle.
// ---------------------------------------------------------------------------
__global__ __launch_bounds__(256) void k_backproj(const __half* __restrict__ y2h,
                                                  float* __restrict__ vol) {
  __shared__ __align__(16) float s_mem[4112];  // ring 16KB | epilogue 16x257
  __shared__ float s_sin[APC];
  __shared__ float s_cos[APC];

  int t = threadIdx.x;
  int lane = t & 63;
  int w = t >> 6;        // wave id 0..3
  int h = lane >> 4;     // k-group 0..3
  int r = lane & 15;     // A-row / B,D-col index

  int tile = blockIdx.x & 255;
  int chunk = blockIdx.x >> 8;
  int a0 = chunk * APC;

  for (int a = t; a < APC; a += 256) {
    float ph = ((float)(a0 + a) + 0.5f) * (PI_F / (float)A_ANG);
    float sv, cv;
    sincosf(ph, &sv, &cv);
    s_sin[a] = sv;
    s_cos[a] = cv;
  }

  int bi = tile >> 4, bj = tile & 15;
  float Xc = 120.0f - (float)(bi * 16);          // tile-center coords
  float Yc = (float)(bj * 16) - 120.0f;
  float Xw = 127.5f - (float)(bi * 16 + 4 * w);  // this wave's first row
  float Ypr = (float)(bj * 16 + r) - 127.5f;     // this lane's column

  // staging constants: entry e = w*128 + i*64 + lane -> (c = e>>4, kp = e&15)
  int e0 = w * 128 + lane;
  int cst0 = (e0 >> 4) * 256 + (e0 & 15);
  int e1 = e0 + 64;
  int cst1 = (e1 >> 4) * 256 + (e1 & 15);

  const uint32_t* y2u = (const uint32_t*)y2h;  // [a][c][256 cell-pairs]
  uint32_t* ring = (uint32_t*)s_mem;

  floatx4 acc[4][2];
#pragma unroll
  for (int m = 0; m < 4; ++m)
#pragma unroll
    for (int n = 0; n < 2; ++n) acc[m][n] = (floatx4){0.f, 0.f, 0.f, 0.f};

  __syncthreads();  // tables ready (no loads in flight yet)

  auto issue = [&](int an, int slot) {
    float sp = s_sin[an], cp = s_cos[an];
    int ib = ((int)floorf(fmaf(Xc, sp, fmaf(Yc, cp, 255.5f))) - 16) & ~1;
    const uint32_t* src = y2u + (size_t)(a0 + an) * 8192 + (ib >> 1);
    uint32_t* lb = ring + slot * 512 + w * 128;
    GLL4(src + cst0, lb);
    GLL4(src + cst1, lb + 64);
  };

  auto compute = [&](int k) {
    float sp = s_sin[k], cp = s_cos[k];
    float uc = fmaf(Xc, sp, fmaf(Yc, cp, 255.5f));
    int ibase = ((int)floorf(uc) - 16) & ~1;
    const uint32_t* rb = ring + (k & (RING - 1)) * 512;
    half8 bf0 = *(const half8*)(rb + r * 16 + 4 * h);          // ch 0..15
    half8 bf1 = *(const half8*)(rb + (16 + r) * 16 + 4 * h);   // ch 16..31
    float um = fmaf(Xw, sp, fmaf(Ypr, cp, 255.5f));
#pragma unroll
    for (int m = 0; m < 4; ++m) {
      float k0f = floorf(um);
      float wf = um - k0f;
      int e = (int)k0f - ibase;
      e = min(30, max(0, e));  // provably [4,29]; med3-fusable clamp
      float w0 = 1.0f - wf;
      union { fp16x2 h; uint32_t u; } p01, p0w, paw;
      p01.h = __builtin_amdgcn_cvt_pkrtz(w0, wf);   // (w0,w1)
      p0w.h = __builtin_amdgcn_cvt_pkrtz(0.f, w0);  // (0,w0)
      paw.h = __builtin_amdgcn_cvt_pkrtz(wf, 0.f);  // (w1,0)
      bool odd = (e & 1) != 0;
      uint32_t lo = odd ? p0w.u : p01.u;
      uint32_t hi = odd ? paw.u : 0u;
      int q = (e >> 1) - 4 * h;  // pattern lands at u32 slot q (and q+1 if odd)
      union { uint32_t u[4]; half8 v; } af;
#pragma unroll
      for (int j2 = 0; j2 < 4; ++j2) {
        uint32_t rj = (q == j2) ? lo : 0u;
        rj = (q == j2 - 1) ? hi : rj;
        af.u[j2] = rj;
      }
      acc[m][0] =
          __builtin_amdgcn_mfma_f32_16x16x32_f16(af.v, bf0, acc[m][0], 0, 0, 0);
      acc[m][1] =
          __builtin_amdgcn_mfma_f32_16x16x32_f16(af.v, bf1, acc[m][1], 0, 0, 0);
      um -= sp;  // next image row: u -= sin
    }
  };

  // prologue: fill pipeline with angles 0..PD-1 (12 glls per wave)
#pragma unroll
  for (int p = 0; p < PD; ++p) issue(p, p & (RING - 1));
  asm volatile("s_waitcnt vmcnt(8)" ::: "memory");  // angles 0,1 landed
  __builtin_amdgcn_s_barrier();

  for (int k = 0; k < APC; k += 2) {
    compute(k);
    compute(k + 1);
    int a1 = k + PD;     a1 = (a1 < APC) ? a1 : (APC - 1);
    int a2 = k + PD + 1; a2 = (a2 < APC) ? a2 : (APC - 1);
    issue(a1, (k + PD) & (RING - 1));
    issue(a2, (k + PD + 1) & (RING - 1));
    asm volatile("s_waitcnt vmcnt(8)" ::: "memory");  // k+2, k+3 landed
    __builtin_amdgcn_s_barrier();
  }

  // drain before reusing s_mem (tail glls still target ring slots)
  asm volatile("s_waitcnt vmcnt(0)" ::: "memory");
  __syncthreads();

  // epilogue: two 16-channel half-passes through a 16x257 LDS transpose,
  // then line-coalesced atomics.  D layout (m89): lane holds
  // px = (4w+m)*16 + 4h+jr, ch = 16n + r.
  const float DPHI = PI_F / (float)A_ANG;
  size_t gbase = ((size_t)(bi * 16) * NVOL + (size_t)(bj * 16)) * CCH;
#pragma unroll
  for (int n = 0; n < 2; ++n) {
    if (n) __syncthreads();  // pass-0 reads done before overwrite
#pragma unroll
    for (int m = 0; m < 4; ++m)
#pragma unroll
      for (int jr = 0; jr < 4; ++jr) {
        int px = (4 * w + m) * 16 + 4 * h + jr;
        s_mem[r * 257 + px] = acc[m][n][jr] * DPHI;
      }
    __syncthreads();
#pragma unroll
    for (int mm = 0; mm < 16; ++mm) {
      int f = mm * 256 + t;
      int c16 = f & 15;
      int p2 = f >> 4;  // pixel 0..255
      int jj = p2 & 15, ii = p2 >> 4;
      float v = s_mem[c16 * 257 + p2];
      atomicAdd(vol + gbase + ((size_t)ii * NVOL + jj) * CCH + 16 * n + c16, v);
    }
  }
}

// ---------------------------------------------------------------------------
// K3: 3x3 causal conv 32->32 + sigmoid.  in/out channel-last [i][j][32].
// ---------------------------------------------------------------------------
__global__ __launch_bounds__(256) void k_conv1(const float* __restrict__ vol,
                                               const float* __restrict__ w1,
                                               const float* __restrict__ b1,
                                               float* __restrict__ out1) {
  __shared__ float wl[9 * CCH * CCH];  // 36 KB: [p][ci][o]
  int t = threadIdx.x;
  for (int e = t; e < 9 * CCH * CCH; e += 256) {
    int o = e & 31;
    int ci = (e >> 5) & 31;
    int p = e >> 10;           // 0..8
    int di = p / 3, dj = p % 3;
    wl[e] = w1[((o * CCH + ci) * 3 + di) * 3 + dj];
  }
  __syncthreads();

  int pix = blockIdx.x * 256 + t;
  int j = pix & 255, i = pix >> 8;

  float acc[CCH];
#pragma unroll
  for (int o = 0; o < CCH; ++o) acc[o] = b1[o];

#pragma unroll 1
  for (int p = 0; p < 9; ++p) {
    int di = p / 3, dj = p % 3;
    int ii = i + di - 2, jj = j + dj - 2;
    if (ii < 0 || jj < 0) continue;   // zero-padded region contributes nothing
    const float4* ip4 = (const float4*)(vol + ((size_t)(ii * NVOL + jj)) * CCH);
    const float* wp = &wl[p * CCH * CCH];
#pragma unroll
    for (int q = 0; q < 8; ++q) {
      float4 v = ip4[q];
      float iv[4] = {v.x, v.y, v.z, v.w};
#pragma unroll
      for (int cc = 0; cc < 4; ++cc) {
        const float4* wv4 = (const float4*)(wp + (4 * q + cc) * CCH);
#pragma unroll
        for (int o4 = 0; o4 < 8; ++o4) {
          float4 wv = wv4[o4];
          acc[o4 * 4 + 0] = fmaf(iv[cc], wv.x, acc[o4 * 4 + 0]);
          acc[o4 * 4 + 1] = fmaf(iv[cc], wv.y, acc[o4 * 4 + 1]);
          acc[o4 * 4 + 2] = fmaf(iv[cc], wv.z, acc[o4 * 4 + 2]);
          acc[o4 * 4 + 3] = fmaf(iv[cc], wv.w, acc[o4 * 4 + 3]);
        }
      }
    }
  }

  float4* op = (float4*)(out1 + (size_t)pix * CCH);
#pragma unroll
  for (int o4 = 0; o4 < 8; ++o4) {
    float4 v;
    v.x = 1.0f / (1.0f + expf(-acc[o4 * 4 + 0]));
    v.y = 1.0f / (1.0f + expf(-acc[o4 * 4 + 1]));
    v.z = 1.0f / (1.0f + expf(-acc[o4 * 4 + 2]));
    v.w = 1.0f / (1.0f + expf(-acc[o4 * 4 + 3]));
    op[o4] = v;
  }
}

// ---------------------------------------------------------------------------
// K4: 3x3 causal conv 32->1 + sigmoid.  out[i][j] row-major (matches ref).
// ---------------------------------------------------------------------------
__global__ __launch_bounds__(256) void k_conv2(const float* __restrict__ s1,
                                               const float* __restrict__ w2,
                                               const float* __restrict__ b2,
                                               float* __restrict__ out) {
  __shared__ float wl[9 * CCH];  // [p][ci]
  int t = threadIdx.x;
  for (int e = t; e < 9 * CCH; e += 256) {
    int ci = e & 31, p = e >> 5;
    int di = p / 3, dj = p % 3;
    wl[e] = w2[ci * 9 + di * 3 + dj];
  }
  __syncthreads();

  int pix = blockIdx.x * 256 + t;
  int j = pix & 255, i = pix >> 8;

  float acc = b2[0];
#pragma unroll 1
  for (int p = 0; p < 9; ++p) {
    int di = p / 3, dj = p % 3;
    int ii = i + di - 2, jj = j + dj - 2;
    if (ii < 0 || jj < 0) continue;
    const float4* ip4 = (const float4*)(s1 + ((size_t)(ii * NVOL + jj)) * CCH);
    const float4* wv4 = (const float4*)(&wl[p * CCH]);
#pragma unroll
    for (int q = 0; q < 8; ++q) {
      float4 v = ip4[q];
      float4 wv = wv4[q];
      acc = fmaf(v.x, wv.x, acc);
      acc = fmaf(v.y, wv.y, acc);
      acc = fmaf(v.z, wv.z, acc);
      acc = fmaf(v.w, wv.w, acc);
    }
  }
  out[pix] = 1.0f / (1.0f + expf(-acc));
}

// ---------------------------------------------------------------------------
extern "C" void kernel_launch(void* const* d_in, const int* in_sizes, int n_in,
                              void* d_out, int out_size, void* d_ws,
                              size_t ws_size, hipStream_t stream) {
  const float* x    = (const float*)d_in[0];  // [1,1,400,512]
  const float* wdet = (const float*)d_in[1];  // [32,1,1,11]
  const float* bdet = (const float*)d_in[2];  // [32]
  const float* w1   = (const float*)d_in[3];  // [32,32,3,3]
  const float* b1   = (const float*)d_in[4];  // [32]
  const float* w2   = (const float*)d_in[5];  // [1,32,3,3]
  const float* b2   = (const float*)d_in[6];  // [1]
  float* out = (float*)d_out;                 // [1,1,256,256]

  float* ws = (float*)d_ws;
  __half* y2h = (__half*)ws;                         // [400][32][512] f16 = 13.1 MB
  float* vol  = ws + (A_ANG * CCH * DDET) / 2;       // [256][256][32] f32 = 8.4 MB
  float* sig1 = vol + NVOL * NVOL * CCH;             // [256][256][32] f32 = 8.4 MB

  k_detconv<<<dim3((A_ANG * CCH * DDET / 2) / 256), dim3(256), 0, stream>>>(
      x, wdet, bdet, y2h);
  // vol accumulated by 8 chunk-blocks per tile via line-coalesced atomics
  (void)hipMemsetAsync(vol, 0, (size_t)NVOL * NVOL * CCH * sizeof(float), stream);
  k_backproj<<<dim3(256 * NCHUNK), dim3(256), 0, stream>>>(y2h, vol);
  k_conv1<<<dim3(256), dim3(256), 0, stream>>>(vol, w1, b1, sig1);
  k_conv2<<<dim3(256), dim3(256), 0, stream>>>(sig1, w2, b2, out);
}

// Round 7
// 206.935 us; speedup vs baseline: 1.1835x; 1.0786x over previous
//
#include <hip/hip_runtime.h>
#include <hip/hip_fp16.h>
#include <math.h>
#include <stdint.h>

#define A_ANG 400
#define DDET  512
#define NVOL  256
#define CCH   32
#define KSZ   11
#define PI_F  3.14159265358979323846f

#define NCHUNK 8
#define APC (A_ANG / NCHUNK)   // 50 angles per block
#define RING 8                 // LDS ring slots (2 KB each, f16)
#define PD   6                 // prefetch distance in angles (2 gll4 per angle)

typedef _Float16 half8 __attribute__((ext_vector_type(8)));
typedef __fp16  fp16x2 __attribute__((ext_vector_type(2)));  // cvt_pkrtz ret type
typedef float   floatx4 __attribute__((ext_vector_type(4)));

typedef __attribute__((address_space(3))) uint32_t       lds_u32;
typedef const __attribute__((address_space(1))) uint32_t glb_u32;
#define GLL4(gp, lp) \
  __builtin_amdgcn_global_load_lds((glb_u32*)(gp), (lds_u32*)(lp), 4, 0, 0)

// ---------------------------------------------------------------------------
// K1: causal detector conv -> f16 CHANNEL-MAJOR y[a][c][d] (packed half2).
// ---------------------------------------------------------------------------
__global__ __launch_bounds__(256) void k_detconv(const float* __restrict__ x,
                                                 const float* __restrict__ wdet,
                                                 const float* __restrict__ bdet,
                                                 __half* __restrict__ y2h) {
  __shared__ float wl[CCH * KSZ];
  __shared__ float bl[CCH];
  int t = threadIdx.x;
  for (int e = t; e < CCH * KSZ; e += 256) wl[e] = wdet[e];
  if (t < CCH) bl[t] = bdet[t];
  __syncthreads();

  int idx = blockIdx.x * 256 + t;  // = a*8192 + c*256 + d2
  int d2 = idx & 255;
  int c = (idx >> 8) & 31;
  int a = idx >> 13;
  const float* xr = x + a * DDET;
  int d0 = 2 * d2;
  float acc0 = bl[c], acc1 = bl[c];
#pragma unroll
  for (int k = 0; k < KSZ; ++k) {
    float wv = wl[c * KSZ + k];
    int dd0 = d0 + k - (KSZ - 1);
    int dd1 = dd0 + 1;
    float xv0 = (dd0 >= 0) ? xr[dd0] : 0.0f;
    float xv1 = (dd1 >= 0) ? xr[dd1] : 0.0f;
    acc0 = fmaf(wv, xv0, acc0);
    acc1 = fmaf(wv, xv1, acc1);
  }
  __half2 hv = __floats2half2_rn(acc0, acc1);
  *reinterpret_cast<__half2*>(y2h + ((size_t)(a * CCH + c) * DDET + d0)) = hv;
}

// ---------------------------------------------------------------------------
// K2: backprojection v7 — A-build dedup across k-groups (bpermute broadcast).
//   v6 built the interpolation pattern per lane per m: lanes (h,r) h=0..3
//   computed IDENTICAL (e,w0,w1) chains (4x redundant).  v7: lane (h,r)
//   builds the pattern for row m==h only (Xwh = Xw - h), packs
//   msg1 = hi | (e>>1)<<16 (hi top16 provably 0), and per m the pattern is
//   fetched from lane 16m+r with 2 ds_bpermute (LDS pipe, folded offset).
//   Chain VALU /4; placement (8 cmp/cndmask) kept.
//   Everything else unchanged from v6 (ring 8 x 2KB, PD=6, vmcnt(8),
//   2 angles/barrier, 2-pass epilogue transpose + coalesced atomics).
// ---------------------------------------------------------------------------
__global__ __launch_bounds__(256) void k_backproj(const __half* __restrict__ y2h,
                                                  float* __restrict__ vol) {
  __shared__ __align__(16) float s_mem[4112];  // ring 16KB | epilogue 16x257
  __shared__ float s_sin[APC];
  __shared__ float s_cos[APC];

  int t = threadIdx.x;
  int lane = t & 63;
  int w = t >> 6;        // wave id 0..3
  int h = lane >> 4;     // k-group 0..3
  int r = lane & 15;     // A-row / B,D-col index

  int tile = blockIdx.x & 255;
  int chunk = blockIdx.x >> 8;
  int a0 = chunk * APC;

  for (int a = t; a < APC; a += 256) {
    float ph = ((float)(a0 + a) + 0.5f) * (PI_F / (float)A_ANG);
    float sv, cv;
    sincosf(ph, &sv, &cv);
    s_sin[a] = sv;
    s_cos[a] = cv;
  }

  int bi = tile >> 4, bj = tile & 15;
  float Xc = 120.0f - (float)(bi * 16);          // tile-center coords
  float Yc = (float)(bj * 16) - 120.0f;
  // lane builds row i = bi*16 + 4w + h, col j = bj*16 + r:
  float Xwh = 127.5f - (float)(bi * 16 + 4 * w + h);
  float Ypr = (float)(bj * 16 + r) - 127.5f;     // this lane's column

  int bpa = r << 2;          // bpermute byte addr of lane (0, r)
  int rdoff = r * 16 + 4 * h;  // B-frag u32 offset (loop-invariant)

  // staging constants: entry e = w*128 + i*64 + lane -> (c = e>>4, kp = e&15)
  int e0 = w * 128 + lane;
  int cst0 = (e0 >> 4) * 256 + (e0 & 15);
  int e1 = e0 + 64;
  int cst1 = (e1 >> 4) * 256 + (e1 & 15);

  const uint32_t* y2u = (const uint32_t*)y2h;  // [a][c][256 cell-pairs]
  uint32_t* ring = (uint32_t*)s_mem;

  floatx4 acc[4][2];
#pragma unroll
  for (int m = 0; m < 4; ++m)
#pragma unroll
    for (int n = 0; n < 2; ++n) acc[m][n] = (floatx4){0.f, 0.f, 0.f, 0.f};

  __syncthreads();  // tables ready (no loads in flight yet)

  auto issue = [&](int an, int slot) {
    float sp = s_sin[an], cp = s_cos[an];
    int ib = ((int)floorf(fmaf(Xc, sp, fmaf(Yc, cp, 255.5f))) - 16) & ~1;
    const uint32_t* src = y2u + (size_t)(a0 + an) * 8192 + (ib >> 1);
    uint32_t* lb = ring + slot * 512 + w * 128;
    GLL4(src + cst0, lb);
    GLL4(src + cst1, lb + 64);
  };

  auto compute = [&](int k) {
    float sp = s_sin[k], cp = s_cos[k];
    float uc = fmaf(Xc, sp, fmaf(Yc, cp, 255.5f));
    int ibase = ((int)floorf(uc) - 16) & ~1;
    const uint32_t* rb = ring + (k & (RING - 1)) * 512;
    half8 bf0 = *(const half8*)(rb + rdoff);          // ch 0..15
    half8 bf1 = *(const half8*)(rb + 256 + rdoff);    // ch 16..31
    // --- build pattern for row m == h (once per lane, not per m) ---
    float us = fmaf(Xwh, sp, fmaf(Ypr, cp, 255.5f));
    float k0f = floorf(us);
    float wf = us - k0f;
    int e = (int)k0f - ibase;
    e = min(30, max(0, e));  // provably [4,29]; med3-fusable clamp
    float w0 = 1.0f - wf;
    union { fp16x2 hh; uint32_t u; } p01, p0w, paw;
    p01.hh = __builtin_amdgcn_cvt_pkrtz(w0, wf);   // (w0,w1)
    p0w.hh = __builtin_amdgcn_cvt_pkrtz(0.f, w0);  // (0,w0)
    paw.hh = __builtin_amdgcn_cvt_pkrtz(wf, 0.f);  // (w1,0)
    bool odd = (e & 1) != 0;
    uint32_t lo = odd ? p0w.u : p01.u;
    uint32_t hi = odd ? paw.u : 0u;                // top 16 bits always 0
    uint32_t msg1 = hi | ((uint32_t)(e >> 1) << 16);
#pragma unroll
    for (int m = 0; m < 4; ++m) {
      // fetch row-m pattern from lane 16m + r (same r, k-group m)
      uint32_t lom = (uint32_t)__builtin_amdgcn_ds_bpermute(bpa + 64 * m, (int)lo);
      uint32_t m1  = (uint32_t)__builtin_amdgcn_ds_bpermute(bpa + 64 * m, (int)msg1);
      int qm = (int)(m1 >> 16) - 4 * h;  // u32 slot within this lane's quarter
      uint32_t him = m1 & 0xFFFFu;
      union { uint32_t u[4]; half8 v; } af;
#pragma unroll
      for (int j2 = 0; j2 < 4; ++j2) {
        uint32_t rj = (qm == j2) ? lom : 0u;
        rj = (qm == j2 - 1) ? him : rj;
        af.u[j2] = rj;
      }
      acc[m][0] =
          __builtin_amdgcn_mfma_f32_16x16x32_f16(af.v, bf0, acc[m][0], 0, 0, 0);
      acc[m][1] =
          __builtin_amdgcn_mfma_f32_16x16x32_f16(af.v, bf1, acc[m][1], 0, 0, 0);
    }
  };

  // prologue: fill pipeline with angles 0..PD-1 (12 glls per wave)
#pragma unroll
  for (int p = 0; p < PD; ++p) issue(p, p & (RING - 1));
  asm volatile("s_waitcnt vmcnt(8)" ::: "memory");  // angles 0,1 landed
  __builtin_amdgcn_s_barrier();

  for (int k = 0; k < APC; k += 2) {
    compute(k);
    compute(k + 1);
    int a1 = k + PD;     a1 = (a1 < APC) ? a1 : (APC - 1);
    int a2 = k + PD + 1; a2 = (a2 < APC) ? a2 : (APC - 1);
    issue(a1, (k + PD) & (RING - 1));
    issue(a2, (k + PD + 1) & (RING - 1));
    asm volatile("s_waitcnt vmcnt(8)" ::: "memory");  // k+2, k+3 landed
    __builtin_amdgcn_s_barrier();
  }

  // drain before reusing s_mem (tail glls still target ring slots)
  asm volatile("s_waitcnt vmcnt(0)" ::: "memory");
  __syncthreads();

  // epilogue: two 16-channel half-passes through a 16x257 LDS transpose,
  // then line-coalesced atomics.  D layout (m89): lane holds
  // px = (4w+m)*16 + 4h+jr, ch = 16n + r.
  const float DPHI = PI_F / (float)A_ANG;
  size_t gbase = ((size_t)(bi * 16) * NVOL + (size_t)(bj * 16)) * CCH;
#pragma unroll
  for (int n = 0; n < 2; ++n) {
    if (n) __syncthreads();  // pass-0 reads done before overwrite
#pragma unroll
    for (int m = 0; m < 4; ++m)
#pragma unroll
      for (int jr = 0; jr < 4; ++jr) {
        int px = (4 * w + m) * 16 + 4 * h + jr;
        s_mem[r * 257 + px] = acc[m][n][jr] * DPHI;
      }
    __syncthreads();
#pragma unroll
    for (int mm = 0; mm < 16; ++mm) {
      int f = mm * 256 + t;
      int c16 = f & 15;
      int p2 = f >> 4;  // pixel 0..255
      int jj = p2 & 15, ii = p2 >> 4;
      float v = s_mem[c16 * 257 + p2];
      atomicAdd(vol + gbase + ((size_t)ii * NVOL + jj) * CCH + 16 * n + c16, v);
    }
  }
}

// ---------------------------------------------------------------------------
// K3: 3x3 causal conv 32->32 + sigmoid, v2: 4 output-channel groups.
// Grid 1024 = 256 pixel-blocks x 4 groups of 8 out-ch -> 4 blocks/CU
// (was 256 blocks = 1/CU, latency-bound).  Same total FLOPs; input reads
// duplicated x4 (vol is L2-resident, 8.4 MB).  LDS 9 KB: [p][ci][o8].
// ---------------------------------------------------------------------------
__global__ __launch_bounds__(256) void k_conv1(const float* __restrict__ vol,
                                               const float* __restrict__ w1,
                                               const float* __restrict__ b1,
                                               float* __restrict__ out1) {
  __shared__ float wl[9 * CCH * 8];  // 9 KB: [p][ci][o8]
  int t = threadIdx.x;
  int g = blockIdx.x >> 8;   // output group 0..3
  int pb = blockIdx.x & 255;
  for (int e = t; e < 9 * CCH * 8; e += 256) {
    int o8 = e & 7;
    int ci = (e >> 3) & 31;
    int p = e >> 8;            // 0..8
    int di = p / 3, dj = p % 3;
    int o = g * 8 + o8;
    wl[e] = w1[((o * CCH + ci) * 3 + di) * 3 + dj];
  }
  __syncthreads();

  int pix = pb * 256 + t;
  int j = pix & 255, i = pix >> 8;

  float acc[8];
#pragma unroll
  for (int o = 0; o < 8; ++o) acc[o] = b1[g * 8 + o];

#pragma unroll 1
  for (int p = 0; p < 9; ++p) {
    int di = p / 3, dj = p % 3;
    int ii = i + di - 2, jj = j + dj - 2;
    if (ii < 0 || jj < 0) continue;   // zero-padded region contributes nothing
    const float4* ip4 = (const float4*)(vol + ((size_t)(ii * NVOL + jj)) * CCH);
    const float* wp = &wl[p * CCH * 8];
#pragma unroll
    for (int q = 0; q < 8; ++q) {
      float4 v = ip4[q];
      float iv[4] = {v.x, v.y, v.z, v.w};
#pragma unroll
      for (int cc = 0; cc < 4; ++cc) {
        const float4* wv4 = (const float4*)(wp + (4 * q + cc) * 8);
        float4 wa = wv4[0], wb = wv4[1];
        acc[0] = fmaf(iv[cc], wa.x, acc[0]);
        acc[1] = fmaf(iv[cc], wa.y, acc[1]);
        acc[2] = fmaf(iv[cc], wa.z, acc[2]);
        acc[3] = fmaf(iv[cc], wa.w, acc[3]);
        acc[4] = fmaf(iv[cc], wb.x, acc[4]);
        acc[5] = fmaf(iv[cc], wb.y, acc[5]);
        acc[6] = fmaf(iv[cc], wb.z, acc[6]);
        acc[7] = fmaf(iv[cc], wb.w, acc[7]);
      }
    }
  }

  float4* op = (float4*)(out1 + (size_t)pix * CCH + g * 8);
#pragma unroll
  for (int o4 = 0; o4 < 2; ++o4) {
    float4 v;
    v.x = 1.0f / (1.0f + expf(-acc[o4 * 4 + 0]));
    v.y = 1.0f / (1.0f + expf(-acc[o4 * 4 + 1]));
    v.z = 1.0f / (1.0f + expf(-acc[o4 * 4 + 2]));
    v.w = 1.0f / (1.0f + expf(-acc[o4 * 4 + 3]));
    op[o4] = v;
  }
}

// ---------------------------------------------------------------------------
// K4: 3x3 causal conv 32->1 + sigmoid.  out[i][j] row-major (matches ref).
// ---------------------------------------------------------------------------
__global__ __launch_bounds__(256) void k_conv2(const float* __restrict__ s1,
                                               const float* __restrict__ w2,
                                               const float* __restrict__ b2,
                                               float* __restrict__ out) {
  __shared__ float wl[9 * CCH];  // [p][ci]
  int t = threadIdx.x;
  for (int e = t; e < 9 * CCH; e += 256) {
    int ci = e & 31, p = e >> 5;
    int di = p / 3, dj = p % 3;
    wl[e] = w2[ci * 9 + di * 3 + dj];
  }
  __syncthreads();

  int pix = blockIdx.x * 256 + t;
  int j = pix & 255, i = pix >> 8;

  float acc = b2[0];
#pragma unroll 1
  for (int p = 0; p < 9; ++p) {
    int di = p / 3, dj = p % 3;
    int ii = i + di - 2, jj = j + dj - 2;
    if (ii < 0 || jj < 0) continue;
    const float4* ip4 = (const float4*)(s1 + ((size_t)(ii * NVOL + jj)) * CCH);
    const float4* wv4 = (const float4*)(&wl[p * CCH]);
#pragma unroll
    for (int q = 0; q < 8; ++q) {
      float4 v = ip4[q];
      float4 wv = wv4[q];
      acc = fmaf(v.x, wv.x, acc);
      acc = fmaf(v.y, wv.y, acc);
      acc = fmaf(v.z, wv.z, acc);
      acc = fmaf(v.w, wv.w, acc);
    }
  }
  out[pix] = 1.0f / (1.0f + expf(-acc));
}

// ---------------------------------------------------------------------------
extern "C" void kernel_launch(void* const* d_in, const int* in_sizes, int n_in,
                              void* d_out, int out_size, void* d_ws,
                              size_t ws_size, hipStream_t stream) {
  const float* x    = (const float*)d_in[0];  // [1,1,400,512]
  const float* wdet = (const float*)d_in[1];  // [32,1,1,11]
  const float* bdet = (const float*)d_in[2];  // [32]
  const float* w1   = (const float*)d_in[3];  // [32,32,3,3]
  const float* b1   = (const float*)d_in[4];  // [32]
  const float* w2   = (const float*)d_in[5];  // [1,32,3,3]
  const float* b2   = (const float*)d_in[6];  // [1]
  float* out = (float*)d_out;                 // [1,1,256,256]

  float* ws = (float*)d_ws;
  __half* y2h = (__half*)ws;                         // [400][32][512] f16 = 13.1 MB
  float* vol  = ws + (A_ANG * CCH * DDET) / 2;       // [256][256][32] f32 = 8.4 MB
  float* sig1 = vol + NVOL * NVOL * CCH;             // [256][256][32] f32 = 8.4 MB

  k_detconv<<<dim3((A_ANG * CCH * DDET / 2) / 256), dim3(256), 0, stream>>>(
      x, wdet, bdet, y2h);
  // vol accumulated by 8 chunk-blocks per tile via line-coalesced atomics
  (void)hipMemsetAsync(vol, 0, (size_t)NVOL * NVOL * CCH * sizeof(float), stream);
  k_backproj<<<dim3(256 * NCHUNK), dim3(256), 0, stream>>>(y2h, vol);
  k_conv1<<<dim3(256 * 4), dim3(256), 0, stream>>>(vol, w1, b1, sig1);
  k_conv2<<<dim3(256), dim3(256), 0, stream>>>(sig1, w2, b2, out);
}

// Round 8
// 178.971 us; speedup vs baseline: 1.3684x; 1.1562x over previous
//
#include <hip/hip_runtime.h>
#include <hip/hip_fp16.h>
#include <math.h>
#include <stdint.h>

#define A_ANG 400
#define DDET  512
#define NVOL  256
#define CCH   32
#define KSZ   11
#define PI_F  3.14159265358979323846f

#define NCHUNK 5
#define APC (A_ANG / NCHUNK)   // 80 angles per block
#define RING 6                 // angle slots; each 4KB (4 waves x 1KB)
#define PD   4                 // prefetch distance in angles (4 gll4 each)

typedef _Float16 half8 __attribute__((ext_vector_type(8)));
typedef __fp16  fp16x2 __attribute__((ext_vector_type(2)));  // cvt_pkrtz ret type
typedef float   floatx4 __attribute__((ext_vector_type(4)));

typedef __attribute__((address_space(3))) uint32_t       lds_u32;
typedef const __attribute__((address_space(1))) uint32_t glb_u32;
#define GLL4(gp, lp) \
  __builtin_amdgcn_global_load_lds((glb_u32*)(gp), (lds_u32*)(lp), 4, 0, 0)

// ---------------------------------------------------------------------------
// K1: causal detector conv -> f16 CHANNEL-MAJOR y[a][c][d] (packed half2).
// ---------------------------------------------------------------------------
__global__ __launch_bounds__(256) void k_detconv(const float* __restrict__ x,
                                                 const float* __restrict__ wdet,
                                                 const float* __restrict__ bdet,
                                                 __half* __restrict__ y2h) {
  __shared__ float wl[CCH * KSZ];
  __shared__ float bl[CCH];
  int t = threadIdx.x;
  for (int e = t; e < CCH * KSZ; e += 256) wl[e] = wdet[e];
  if (t < CCH) bl[t] = bdet[t];
  __syncthreads();

  int idx = blockIdx.x * 256 + t;  // = a*8192 + c*256 + d2
  int d2 = idx & 255;
  int c = (idx >> 8) & 31;
  int a = idx >> 13;
  const float* xr = x + a * DDET;
  int d0 = 2 * d2;
  float acc0 = bl[c], acc1 = bl[c];
#pragma unroll
  for (int k = 0; k < KSZ; ++k) {
    float wv = wl[c * KSZ + k];
    int dd0 = d0 + k - (KSZ - 1);
    int dd1 = dd0 + 1;
    float xv0 = (dd0 >= 0) ? xr[dd0] : 0.0f;
    float xv1 = (dd1 >= 0) ? xr[dd1] : 0.0f;
    acc0 = fmaf(wv, xv0, acc0);
    acc1 = fmaf(wv, xv1, acc1);
  }
  __half2 hv = __floats2half2_rn(acc0, acc1);
  *reinterpret_cast<__half2*>(y2h + ((size_t)(a * CCH + c) * DDET + d0)) = hv;
}

// ---------------------------------------------------------------------------
// K2: backprojection v8 — 2 angles per MFMA (K=32 = 2 x 16-cell windows),
// 8x8 px wave-tiles, barrier-free main loop.
//   - wave w owns an 8x8 sub-tile; 16-cell window suffices:
//     |u-ucw| <= 3.5*(|s|+|c|) <= 4.95; ibw=(floor(ucw)-7)&~1 -> e in [2,13],
//     e+1 <= 14 < 16, never straddles the packed-angle boundary.
//   - lane (h,r): angle g=h>>1, M-index r -> px (i8=2m+(r>>3), j8=r&7).
//     A-chain built LOCALLY per angle-half (no bpermute); selects halve.
//   - MFMA per angle: 4 (was 8); B-read per angle: 1 ds_read_b128.
//   - windows are WAVE-PRIVATE -> no __syncthreads in main loop; each wave
//     pipelines on its own vmcnt (ring 6 angle-slots, PD=4, vmcnt(8)).
//   - epilogue unchanged: 2-pass 16x257 transpose + coalesced atomics.
// ---------------------------------------------------------------------------
__global__ __launch_bounds__(256) void k_backproj(const __half* __restrict__ y2h,
                                                  float* __restrict__ vol) {
  __shared__ __align__(16) uint32_t s_ring[RING * 1024];  // 24KB; epi reuse
  __shared__ float s_sin[APC];
  __shared__ float s_cos[APC];

  int t = threadIdx.x;
  int lane = t & 63;
  int w = t >> 6;        // wave id 0..3
  int h = lane >> 4;     // k-group 0..3: angle g=h>>1, cell-half h&1
  int r = lane & 15;     // A-row / B,D-col index

  int tile = blockIdx.x & 255;   // grid = 256*NCHUNK, 256 = pow2 ok
  int chunk = blockIdx.x >> 8;
  int a0 = chunk * APC;

  for (int a = t; a < APC; a += 256) {
    float ph = ((float)(a0 + a) + 0.5f) * (PI_F / (float)A_ANG);
    float sv, cv;
    sincosf(ph, &sv, &cv);
    s_sin[a] = sv;
    s_cos[a] = cv;
  }

  int bi = tile >> 4, bj = tile & 15;
  int wi = w >> 1, wj = w & 1;   // wave-tile position (2x2 of 8x8)
  float Xcw = 124.0f - (float)(bi * 16 + 8 * wi);        // 127.5-(base+3.5)
  float Ycw = (float)(bj * 16 + 8 * wj) - 124.0f;
  float Xl0 = 127.5f - (float)(bi * 16 + 8 * wi + (r >> 3));  // m=0 row
  float Yl  = (float)(bj * 16 + 8 * wj + (r & 7)) - 127.5f;

  // staging map: entry e = i2*64 + lane -> (c = e>>3, p = e&7)
  int goff0 = ((lane >> 3) << 8) + (lane & 7);  // c*256 + p for i2=0
  int hh = h & 1;
  int rdoff0 = r * 8 + hh * 4;          // B-frag u32 offset, ch 0..15
  int rdoff1 = (16 + r) * 8 + hh * 4;   // ch 16..31

  const uint32_t* y2u = (const uint32_t*)y2h;  // [a][c][256 cell-pairs]

  floatx4 acc[4][2];
#pragma unroll
  for (int m = 0; m < 4; ++m)
#pragma unroll
    for (int n = 0; n < 2; ++n) acc[m][n] = (floatx4){0.f, 0.f, 0.f, 0.f};

  __syncthreads();  // tables ready (no loads in flight yet)

  auto issue = [&](int an, int slot) {
    float sp = s_sin[an], cp = s_cos[an];
    float ucw = fmaf(Xcw, sp, fmaf(Ycw, cp, 255.5f));
    int ibw = ((int)floorf(ucw) - 7) & ~1;
    const uint32_t* src = y2u + (size_t)(a0 + an) * 8192 + (ibw >> 1) + goff0;
    uint32_t* lb = s_ring + slot * 1024 + w * 256;
#pragma unroll
    for (int i2 = 0; i2 < 4; ++i2) GLL4(src + i2 * 2048, lb + i2 * 64);
  };

  auto computePair = [&](int k, int sl0, int sl1) {
    int ga = h >> 1;                  // this lane's packed angle (0 or 1)
    int ak = k + ga;
    int sa = ga ? sl1 : sl0;
    float sp = s_sin[ak], cp = s_cos[ak];
    float ucw = fmaf(Xcw, sp, fmaf(Ycw, cp, 255.5f));
    int ibw = ((int)floorf(ucw) - 7) & ~1;
    const uint32_t* rbw = s_ring + sa * 1024 + w * 256;
    half8 bf0 = *(const half8*)(rbw + rdoff0);   // ch 0..15, cells 8hh..+7
    half8 bf1 = *(const half8*)(rbw + rdoff1);   // ch 16..31
    float us = fmaf(Xl0, sp, fmaf(Yl, cp, 255.5f));
#pragma unroll
    for (int m = 0; m < 4; ++m) {
      float k0f = floorf(us);
      float wf = us - k0f;
      int e = (int)k0f - ibw;
      e = min(14, max(0, e));  // provably [2,13]
      float w0 = 1.0f - wf;
      union { fp16x2 hv; uint32_t u; } p01, p0w, paw;
      p01.hv = __builtin_amdgcn_cvt_pkrtz(w0, wf);   // (w0,w1)
      p0w.hv = __builtin_amdgcn_cvt_pkrtz(0.f, w0);  // (0,w0)
      paw.hv = __builtin_amdgcn_cvt_pkrtz(wf, 0.f);  // (w1,0)
      bool odd = (e & 1) != 0;
      uint32_t lo = odd ? p0w.u : p01.u;
      uint32_t hi = odd ? paw.u : 0u;
      int qm = (e >> 1) - 4 * hh;  // pattern pair-slot within lane's quarter
      union { uint32_t u[4]; half8 v; } af;
#pragma unroll
      for (int j2 = 0; j2 < 4; ++j2) {
        uint32_t rj = (qm == j2) ? lo : 0u;
        rj = (qm == j2 - 1) ? hi : rj;
        af.u[j2] = rj;
      }
      acc[m][0] =
          __builtin_amdgcn_mfma_f32_16x16x32_f16(af.v, bf0, acc[m][0], 0, 0, 0);
      acc[m][1] =
          __builtin_amdgcn_mfma_f32_16x16x32_f16(af.v, bf1, acc[m][1], 0, 0, 0);
      us = fmaf(-2.0f, sp, us);  // next image row: i += 2
    }
  };

  // prologue: angles 0..3 into slots 0..3 (16 glls/wave)
#pragma unroll
  for (int p = 0; p < PD; ++p) issue(p, p);
  asm volatile("s_waitcnt vmcnt(8)" ::: "memory");  // angles 0,1 landed
  // NOTE: no barrier — ring regions are wave-private.

  int sk = 0;  // slot of angle k
  for (int k = 0; k < APC; k += 2) {
    int s1 = sk + 1; if (s1 >= RING) s1 -= RING;
    computePair(k, sk, s1);
    int s4 = sk + 4; if (s4 >= RING) s4 -= RING;
    int s5 = s4 + 1; if (s5 >= RING) s5 -= RING;
    int a4 = k + 4; a4 = (a4 < APC) ? a4 : (APC - 1);
    int a5 = k + 5; a5 = (a5 < APC) ? a5 : (APC - 1);
    issue(a4, s4);
    issue(a5, s5);
    asm volatile("s_waitcnt vmcnt(8)" ::: "memory");  // k+2,k+3 landed
    sk += 2; if (sk >= RING) sk -= RING;
  }

  // drain, then block-wide reuse of s_ring as epilogue buffer
  asm volatile("s_waitcnt vmcnt(0)" ::: "memory");
  __syncthreads();

  // epilogue: two 16-channel half-passes through 16x257 transpose, then
  // line-coalesced atomics.  Lane holds D rows p=4h+jr, col r (=ch 16n+r);
  // px: i_loc = 8wi + 2m + (p>>3), j_loc = 8wj + (p&7).
  float* s_epi = (float*)s_ring;
  const float DPHI = PI_F / (float)A_ANG;
  size_t gbase = ((size_t)(bi * 16) * NVOL + (size_t)(bj * 16)) * CCH;
#pragma unroll
  for (int n = 0; n < 2; ++n) {
    if (n) __syncthreads();  // pass-0 reads done before overwrite
#pragma unroll
    for (int m = 0; m < 4; ++m)
#pragma unroll
      for (int jr = 0; jr < 4; ++jr) {
        int p = 4 * h + jr;
        int px = (8 * wi + 2 * m + (p >> 3)) * 16 + 8 * wj + (p & 7);
        s_epi[r * 257 + px] = acc[m][n][jr] * DPHI;
      }
    __syncthreads();
#pragma unroll
    for (int mm = 0; mm < 16; ++mm) {
      int f = mm * 256 + t;
      int c16 = f & 15;
      int p2 = f >> 4;  // pixel 0..255
      int jj = p2 & 15, ii = p2 >> 4;
      float v = s_epi[c16 * 257 + p2];
      atomicAdd(vol + gbase + ((size_t)ii * NVOL + jj) * CCH + 16 * n + c16, v);
    }
  }
}

// ---------------------------------------------------------------------------
// K3: 3x3 causal conv 32->32 + sigmoid, 4 output-channel groups (4 blk/CU).
// ---------------------------------------------------------------------------
__global__ __launch_bounds__(256) void k_conv1(const float* __restrict__ vol,
                                               const float* __restrict__ w1,
                                               const float* __restrict__ b1,
                                               float* __restrict__ out1) {
  __shared__ float wl[9 * CCH * 8];  // 9 KB: [p][ci][o8]
  int t = threadIdx.x;
  int g = blockIdx.x >> 8;   // output group 0..3
  int pb = blockIdx.x & 255;
  for (int e = t; e < 9 * CCH * 8; e += 256) {
    int o8 = e & 7;
    int ci = (e >> 3) & 31;
    int p = e >> 8;            // 0..8
    int di = p / 3, dj = p % 3;
    int o = g * 8 + o8;
    wl[e] = w1[((o * CCH + ci) * 3 + di) * 3 + dj];
  }
  __syncthreads();

  int pix = pb * 256 + t;
  int j = pix & 255, i = pix >> 8;

  float acc[8];
#pragma unroll
  for (int o = 0; o < 8; ++o) acc[o] = b1[g * 8 + o];

#pragma unroll 1
  for (int p = 0; p < 9; ++p) {
    int di = p / 3, dj = p % 3;
    int ii = i + di - 2, jj = j + dj - 2;
    if (ii < 0 || jj < 0) continue;   // zero-padded region contributes nothing
    const float4* ip4 = (const float4*)(vol + ((size_t)(ii * NVOL + jj)) * CCH);
    const float* wp = &wl[p * CCH * 8];
#pragma unroll
    for (int q = 0; q < 8; ++q) {
      float4 v = ip4[q];
      float iv[4] = {v.x, v.y, v.z, v.w};
#pragma unroll
      for (int cc = 0; cc < 4; ++cc) {
        const float4* wv4 = (const float4*)(wp + (4 * q + cc) * 8);
        float4 wa = wv4[0], wb = wv4[1];
        acc[0] = fmaf(iv[cc], wa.x, acc[0]);
        acc[1] = fmaf(iv[cc], wa.y, acc[1]);
        acc[2] = fmaf(iv[cc], wa.z, acc[2]);
        acc[3] = fmaf(iv[cc], wa.w, acc[3]);
        acc[4] = fmaf(iv[cc], wb.x, acc[4]);
        acc[5] = fmaf(iv[cc], wb.y, acc[5]);
        acc[6] = fmaf(iv[cc], wb.z, acc[6]);
        acc[7] = fmaf(iv[cc], wb.w, acc[7]);
      }
    }
  }

  float4* op = (float4*)(out1 + (size_t)pix * CCH + g * 8);
#pragma unroll
  for (int o4 = 0; o4 < 2; ++o4) {
    float4 v;
    v.x = 1.0f / (1.0f + expf(-acc[o4 * 4 + 0]));
    v.y = 1.0f / (1.0f + expf(-acc[o4 * 4 + 1]));
    v.z = 1.0f / (1.0f + expf(-acc[o4 * 4 + 2]));
    v.w = 1.0f / (1.0f + expf(-acc[o4 * 4 + 3]));
    op[o4] = v;
  }
}

// ---------------------------------------------------------------------------
// K4: 3x3 causal conv 32->1 + sigmoid.  out[i][j] row-major (matches ref).
// ---------------------------------------------------------------------------
__global__ __launch_bounds__(256) void k_conv2(const float* __restrict__ s1,
                                               const float* __restrict__ w2,
                                               const float* __restrict__ b2,
                                               float* __restrict__ out) {
  __shared__ float wl[9 * CCH];  // [p][ci]
  int t = threadIdx.x;
  for (int e = t; e < 9 * CCH; e += 256) {
    int ci = e & 31, p = e >> 5;
    int di = p / 3, dj = p % 3;
    wl[e] = w2[ci * 9 + di * 3 + dj];
  }
  __syncthreads();

  int pix = blockIdx.x * 256 + t;
  int j = pix & 255, i = pix >> 8;

  float acc = b2[0];
#pragma unroll 1
  for (int p = 0; p < 9; ++p) {
    int di = p / 3, dj = p % 3;
    int ii = i + di - 2, jj = j + dj - 2;
    if (ii < 0 || jj < 0) continue;
    const float4* ip4 = (const float4*)(s1 + ((size_t)(ii * NVOL + jj)) * CCH);
    const float4* wv4 = (const float4*)(&wl[p * CCH]);
#pragma unroll
    for (int q = 0; q < 8; ++q) {
      float4 v = ip4[q];
      float4 wv = wv4[q];
      acc = fmaf(v.x, wv.x, acc);
      acc = fmaf(v.y, wv.y, acc);
      acc = fmaf(v.z, wv.z, acc);
      acc = fmaf(v.w, wv.w, acc);
    }
  }
  out[pix] = 1.0f / (1.0f + expf(-acc));
}

// ---------------------------------------------------------------------------
extern "C" void kernel_launch(void* const* d_in, const int* in_sizes, int n_in,
                              void* d_out, int out_size, void* d_ws,
                              size_t ws_size, hipStream_t stream) {
  const float* x    = (const float*)d_in[0];  // [1,1,400,512]
  const float* wdet = (const float*)d_in[1];  // [32,1,1,11]
  const float* bdet = (const float*)d_in[2];  // [32]
  const float* w1   = (const float*)d_in[3];  // [32,32,3,3]
  const float* b1   = (const float*)d_in[4];  // [32]
  const float* w2   = (const float*)d_in[5];  // [1,32,3,3]
  const float* b2   = (const float*)d_in[6];  // [1]
  float* out = (float*)d_out;                 // [1,1,256,256]

  float* ws = (float*)d_ws;
  __half* y2h = (__half*)ws;                         // [400][32][512] f16 = 13.1 MB
  float* vol  = ws + (A_ANG * CCH * DDET) / 2;       // [256][256][32] f32 = 8.4 MB
  float* sig1 = vol + NVOL * NVOL * CCH;             // [256][256][32] f32 = 8.4 MB

  k_detconv<<<dim3((A_ANG * CCH * DDET / 2) / 256), dim3(256), 0, stream>>>(
      x, wdet, bdet, y2h);
  // vol accumulated by 5 chunk-blocks per tile via line-coalesced atomics
  (void)hipMemsetAsync(vol, 0, (size_t)NVOL * NVOL * CCH * sizeof(float), stream);
  k_backproj<<<dim3(256 * NCHUNK), dim3(256), 0, stream>>>(y2h, vol);
  k_conv1<<<dim3(256 * 4), dim3(256), 0, stream>>>(vol, w1, b1, sig1);
  k_conv2<<<dim3(256), dim3(256), 0, stream>>>(sig1, w2, b2, out);
}

// Round 9
// 169.555 us; speedup vs baseline: 1.4444x; 1.0555x over previous
//
#include <hip/hip_runtime.h>
#include <hip/hip_fp16.h>
#include <math.h>
#include <stdint.h>

#define A_ANG 400
#define DDET  512
#define NVOL  256
#define CCH   32
#define KSZ   11
#define PI_F  3.14159265358979323846f

#define NCHUNK 4
#define APC (A_ANG / NCHUNK)   // 100 angles per block
#define RING 6                 // angle slots; each 4KB (4 waves x 1KB)
#define PD   4                 // prefetch distance in angles (4 gll4 each)

typedef _Float16 half8 __attribute__((ext_vector_type(8)));
typedef __fp16  fp16x2 __attribute__((ext_vector_type(2)));  // cvt_pkrtz ret type
typedef float   floatx4 __attribute__((ext_vector_type(4)));

typedef __attribute__((address_space(3))) uint32_t       lds_u32;
typedef const __attribute__((address_space(1))) uint32_t glb_u32;
#define GLL4(gp, lp) \
  __builtin_amdgcn_global_load_lds((glb_u32*)(gp), (lds_u32*)(lp), 4, 0, 0)

// ---------------------------------------------------------------------------
// K1: causal detector conv -> f16 CHANNEL-MAJOR y[a][c][d] (packed half2).
// ---------------------------------------------------------------------------
__global__ __launch_bounds__(256) void k_detconv(const float* __restrict__ x,
                                                 const float* __restrict__ wdet,
                                                 const float* __restrict__ bdet,
                                                 __half* __restrict__ y2h) {
  __shared__ float wl[CCH * KSZ];
  __shared__ float bl[CCH];
  int t = threadIdx.x;
  for (int e = t; e < CCH * KSZ; e += 256) wl[e] = wdet[e];
  if (t < CCH) bl[t] = bdet[t];
  __syncthreads();

  int idx = blockIdx.x * 256 + t;  // = a*8192 + c*256 + d2
  int d2 = idx & 255;
  int c = (idx >> 8) & 31;
  int a = idx >> 13;
  const float* xr = x + a * DDET;
  int d0 = 2 * d2;
  float acc0 = bl[c], acc1 = bl[c];
#pragma unroll
  for (int k = 0; k < KSZ; ++k) {
    float wv = wl[c * KSZ + k];
    int dd0 = d0 + k - (KSZ - 1);
    int dd1 = dd0 + 1;
    float xv0 = (dd0 >= 0) ? xr[dd0] : 0.0f;
    float xv1 = (dd1 >= 0) ? xr[dd1] : 0.0f;
    acc0 = fmaf(wv, xv0, acc0);
    acc1 = fmaf(wv, xv1, acc1);
  }
  __half2 hv = __floats2half2_rn(acc0, acc1);
  *reinterpret_cast<__half2*>(y2h + ((size_t)(a * CCH + c) * DDET + d0)) = hv;
}

// ---------------------------------------------------------------------------
// K2: backprojection v9 — v8 + (a) launch_bounds(256,4)+NCHUNK=4: VGPR cap
// 128 (was 56, suspected rematerialization bloat); (b) hh-dedup: lanes h,h+1
// of the same angle no longer duplicate the lerp chain — each lane owns
// m in {2hh, 2hh+1}, patterns exchanged with ds_bpermute (invariant addrs);
// (c) saddr hoisting: readfirstlane the uniform window base in issue() so
// global addressing runs on SALU, voffsets are loop-invariant VGPRs.
// Window/packing math unchanged from v8 (e in [2,13] proof).
// ---------------------------------------------------------------------------
__global__ __launch_bounds__(256, 4) void k_backproj(const __half* __restrict__ y2h,
                                                     float* __restrict__ vol) {
  __shared__ __align__(16) uint32_t s_ring[RING * 1024];  // 24KB; epi reuse
  __shared__ float s_sin[APC];
  __shared__ float s_cos[APC];

  int t = threadIdx.x;
  int lane = t & 63;
  int w = t >> 6;        // wave id 0..3
  int h = lane >> 4;     // k-group 0..3: angle ga=h>>1, cell-half hh=h&1
  int r = lane & 15;     // A-row / B,D-col index

  int tile = blockIdx.x & 255;
  int chunk = blockIdx.x >> 8;
  int a0 = chunk * APC;

  for (int a = t; a < APC; a += 256) {
    float ph = ((float)(a0 + a) + 0.5f) * (PI_F / (float)A_ANG);
    float sv, cv;
    sincosf(ph, &sv, &cv);
    s_sin[a] = sv;
    s_cos[a] = cv;
  }

  int bi = tile >> 4, bj = tile & 15;
  int wi = w >> 1, wj = w & 1;   // wave-tile position (2x2 of 8x8)
  int hh = h & 1;
  int ga = h >> 1;
  float Xcw = 124.0f - (float)(bi * 16 + 8 * wi);        // 127.5-(base+3.5)
  float Ycw = (float)(bj * 16 + 8 * wj) - 124.0f;
  // this lane OWNS chains for rows i = 4hh + (r>>3) and +2 (m = 2hh, 2hh+1)
  float Xlh = 127.5f - (float)(bi * 16 + 8 * wi + 4 * hh + (r >> 3));
  float Yl  = (float)(bj * 16 + 8 * wj + (r & 7)) - 127.5f;

  // bpermute byte addrs of the owners of m=0,1 (hh=0) and m=2,3 (hh=1),
  // same angle (h&2 preserved) — loop-invariant.
  int bpaA = (((h & 2) | 0) * 16 + r) << 2;
  int bpaB = (((h & 2) | 1) * 16 + r) << 2;

  // staging voffsets (invariant): entry e = i2*64 + lane -> (c=e>>3, p=e&7)
  int goffv[4];
#pragma unroll
  for (int i2 = 0; i2 < 4; ++i2)
    goffv[i2] = ((lane >> 3) << 8) + (lane & 7) + i2 * 2048;
  int rdoff0 = r * 8 + hh * 4;          // B-frag u32 offset, ch 0..15
  int rdoff1 = (16 + r) * 8 + hh * 4;   // ch 16..31

  const uint32_t* y2a = (const uint32_t*)y2h + (size_t)a0 * 8192;

  floatx4 acc[4][2];
#pragma unroll
  for (int m = 0; m < 4; ++m)
#pragma unroll
    for (int n = 0; n < 2; ++n) acc[m][n] = (floatx4){0.f, 0.f, 0.f, 0.f};

  __syncthreads();  // tables ready (no loads in flight yet)

  auto issue = [&](int an, int slot) {
    float sp = s_sin[an], cp = s_cos[an];
    float ucw = fmaf(Xcw, sp, fmaf(Ycw, cp, 255.5f));
    int ibw = ((int)floorf(ucw) - 7) & ~1;    // wave-uniform here (an scalar)
    int wb = __builtin_amdgcn_readfirstlane(an * 8192 + (ibw >> 1));
    const uint32_t* src = y2a + wb;           // SGPR base; voffsets in VGPR
    uint32_t* lb = s_ring + slot * 1024 + w * 256;
#pragma unroll
    for (int i2 = 0; i2 < 4; ++i2) GLL4(src + goffv[i2], lb + i2 * 64);
  };

  auto computePair = [&](int k, int sl0, int sl1) {
    int ak = k + ga;                  // lane's packed angle
    int sa = ga ? sl1 : sl0;
    float sp = s_sin[ak], cp = s_cos[ak];
    float ucw = fmaf(Xcw, sp, fmaf(Ycw, cp, 255.5f));
    int ibw = ((int)floorf(ucw) - 7) & ~1;   // uniform per ga-half only
    const uint32_t* rbw = s_ring + sa * 1024 + w * 256;
    half8 bf0 = *(const half8*)(rbw + rdoff0);   // ch 0..15
    half8 bf1 = *(const half8*)(rbw + rdoff1);   // ch 16..31
    // --- own 2 chains (m = 2hh, 2hh+1): rows 4hh+(r>>3), +2 ---
    uint32_t lov[2], msgv[2];
    float us = fmaf(Xlh, sp, fmaf(Yl, cp, 255.5f));
#pragma unroll
    for (int cch = 0; cch < 2; ++cch) {
      float fl = floorf(us);
      float wf = us - fl;
      int e = (int)fl - ibw;
      e = min(14, max(0, e));  // provably [2,13]
      float w0 = 1.0f - wf;
      union { fp16x2 hv; uint32_t u; } p01, p0w, paw;
      p01.hv = __builtin_amdgcn_cvt_pkrtz(w0, wf);   // (w0,w1)
      p0w.hv = __builtin_amdgcn_cvt_pkrtz(0.f, w0);  // (0,w0)
      paw.hv = __builtin_amdgcn_cvt_pkrtz(wf, 0.f);  // (w1,0) top16=0
      bool odd = (e & 1) != 0;
      lov[cch] = odd ? p0w.u : p01.u;
      uint32_t hi = odd ? paw.u : 0u;
      msgv[cch] = hi | ((uint32_t)(e >> 1) << 16);
      us = fmaf(-2.0f, sp, us);  // next owned row (i += 2)
    }
#pragma unroll
    for (int m = 0; m < 4; ++m) {
      int bpa = (m < 2) ? bpaA : bpaB;
      uint32_t lom =
          (uint32_t)__builtin_amdgcn_ds_bpermute(bpa, (int)((m & 1) ? lov[1] : lov[0]));
      uint32_t mm =
          (uint32_t)__builtin_amdgcn_ds_bpermute(bpa, (int)((m & 1) ? msgv[1] : msgv[0]));
      int qm = (int)(mm >> 16) - 4 * hh;
      uint32_t him = mm & 0xFFFFu;
      union { uint32_t u[4]; half8 v; } af;
#pragma unroll
      for (int j2 = 0; j2 < 4; ++j2) {
        uint32_t rj = (qm == j2) ? lom : 0u;
        rj = (qm == j2 - 1) ? him : rj;
        af.u[j2] = rj;
      }
      acc[m][0] =
          __builtin_amdgcn_mfma_f32_16x16x32_f16(af.v, bf0, acc[m][0], 0, 0, 0);
      acc[m][1] =
          __builtin_amdgcn_mfma_f32_16x16x32_f16(af.v, bf1, acc[m][1], 0, 0, 0);
    }
  };

  // prologue: angles 0..3 into slots 0..3 (16 glls/wave)
#pragma unroll
  for (int p = 0; p < PD; ++p) issue(p, p);
  asm volatile("s_waitcnt vmcnt(8)" ::: "memory");  // angles 0,1 landed
  // no barrier — ring regions are wave-private.

  int sk = 0;  // slot of angle k
  for (int k = 0; k < APC; k += 2) {
    int s1 = sk + 1; if (s1 >= RING) s1 -= RING;
    computePair(k, sk, s1);
    int s4 = sk + 4; if (s4 >= RING) s4 -= RING;
    int s5 = s4 + 1; if (s5 >= RING) s5 -= RING;
    int a4 = k + 4; a4 = (a4 < APC) ? a4 : (APC - 1);
    int a5 = k + 5; a5 = (a5 < APC) ? a5 : (APC - 1);
    issue(a4, s4);
    issue(a5, s5);
    asm volatile("s_waitcnt vmcnt(8)" ::: "memory");  // k+2,k+3 landed
    sk += 2; if (sk >= RING) sk -= RING;
  }

  // drain, then block-wide reuse of s_ring as epilogue buffer
  asm volatile("s_waitcnt vmcnt(0)" ::: "memory");
  __syncthreads();

  // epilogue: two 16-channel half-passes through 16x257 transpose, then
  // line-coalesced atomics.  Lane holds D rows p=4h+jr, col r (=ch 16n+r);
  // px: i_loc = 8wi + 2m + (p>>3), j_loc = 8wj + (p&7).
  float* s_epi = (float*)s_ring;
  const float DPHI = PI_F / (float)A_ANG;
  size_t gbase = ((size_t)(bi * 16) * NVOL + (size_t)(bj * 16)) * CCH;
#pragma unroll
  for (int n = 0; n < 2; ++n) {
    if (n) __syncthreads();  // pass-0 reads done before overwrite
#pragma unroll
    for (int m = 0; m < 4; ++m)
#pragma unroll
      for (int jr = 0; jr < 4; ++jr) {
        int p = 4 * h + jr;
        int px = (8 * wi + 2 * m + (p >> 3)) * 16 + 8 * wj + (p & 7);
        s_epi[r * 257 + px] = acc[m][n][jr] * DPHI;
      }
    __syncthreads();
#pragma unroll
    for (int mm = 0; mm < 16; ++mm) {
      int f = mm * 256 + t;
      int c16 = f & 15;
      int p2 = f >> 4;  // pixel 0..255
      int jj = p2 & 15, ii = p2 >> 4;
      float v = s_epi[c16 * 257 + p2];
      atomicAdd(vol + gbase + ((size_t)ii * NVOL + jj) * CCH + 16 * n + c16, v);
    }
  }
}

// ---------------------------------------------------------------------------
// K3: 3x3 causal conv 32->32 + sigmoid, 4 output-channel groups (4 blk/CU).
// ---------------------------------------------------------------------------
__global__ __launch_bounds__(256) void k_conv1(const float* __restrict__ vol,
                                               const float* __restrict__ w1,
                                               const float* __restrict__ b1,
                                               float* __restrict__ out1) {
  __shared__ float wl[9 * CCH * 8];  // 9 KB: [p][ci][o8]
  int t = threadIdx.x;
  int g = blockIdx.x >> 8;   // output group 0..3
  int pb = blockIdx.x & 255;
  for (int e = t; e < 9 * CCH * 8; e += 256) {
    int o8 = e & 7;
    int ci = (e >> 3) & 31;
    int p = e >> 8;            // 0..8
    int di = p / 3, dj = p % 3;
    int o = g * 8 + o8;
    wl[e] = w1[((o * CCH + ci) * 3 + di) * 3 + dj];
  }
  __syncthreads();

  int pix = pb * 256 + t;
  int j = pix & 255, i = pix >> 8;

  float acc[8];
#pragma unroll
  for (int o = 0; o < 8; ++o) acc[o] = b1[g * 8 + o];

#pragma unroll 1
  for (int p = 0; p < 9; ++p) {
    int di = p / 3, dj = p % 3;
    int ii = i + di - 2, jj = j + dj - 2;
    if (ii < 0 || jj < 0) continue;   // zero-padded region contributes nothing
    const float4* ip4 = (const float4*)(vol + ((size_t)(ii * NVOL + jj)) * CCH);
    const float* wp = &wl[p * CCH * 8];
#pragma unroll
    for (int q = 0; q < 8; ++q) {
      float4 v = ip4[q];
      float iv[4] = {v.x, v.y, v.z, v.w};
#pragma unroll
      for (int cc = 0; cc < 4; ++cc) {
        const float4* wv4 = (const float4*)(wp + (4 * q + cc) * 8);
        float4 wa = wv4[0], wb = wv4[1];
        acc[0] = fmaf(iv[cc], wa.x, acc[0]);
        acc[1] = fmaf(iv[cc], wa.y, acc[1]);
        acc[2] = fmaf(iv[cc], wa.z, acc[2]);
        acc[3] = fmaf(iv[cc], wa.w, acc[3]);
        acc[4] = fmaf(iv[cc], wb.x, acc[4]);
        acc[5] = fmaf(iv[cc], wb.y, acc[5]);
        acc[6] = fmaf(iv[cc], wb.z, acc[6]);
        acc[7] = fmaf(iv[cc], wb.w, acc[7]);
      }
    }
  }

  float4* op = (float4*)(out1 + (size_t)pix * CCH + g * 8);
#pragma unroll
  for (int o4 = 0; o4 < 2; ++o4) {
    float4 v;
    v.x = 1.0f / (1.0f + expf(-acc[o4 * 4 + 0]));
    v.y = 1.0f / (1.0f + expf(-acc[o4 * 4 + 1]));
    v.z = 1.0f / (1.0f + expf(-acc[o4 * 4 + 2]));
    v.w = 1.0f / (1.0f + expf(-acc[o4 * 4 + 3]));
    op[o4] = v;
  }
}

// ---------------------------------------------------------------------------
// K4: 3x3 causal conv 32->1 + sigmoid.  out[i][j] row-major (matches ref).
// ---------------------------------------------------------------------------
__global__ __launch_bounds__(256) void k_conv2(const float* __restrict__ s1,
                                               const float* __restrict__ w2,
                                               const float* __restrict__ b2,
                                               float* __restrict__ out) {
  __shared__ float wl[9 * CCH];  // [p][ci]
  int t = threadIdx.x;
  for (int e = t; e < 9 * CCH; e += 256) {
    int ci = e & 31, p = e >> 5;
    int di = p / 3, dj = p % 3;
    wl[e] = w2[ci * 9 + di * 3 + dj];
  }
  __syncthreads();

  int pix = blockIdx.x * 256 + t;
  int j = pix & 255, i = pix >> 8;

  float acc = b2[0];
#pragma unroll 1
  for (int p = 0; p < 9; ++p) {
    int di = p / 3, dj = p % 3;
    int ii = i + di - 2, jj = j + dj - 2;
    if (ii < 0 || jj < 0) continue;
    const float4* ip4 = (const float4*)(s1 + ((size_t)(ii * NVOL + jj)) * CCH);
    const float4* wv4 = (const float4*)(&wl[p * CCH]);
#pragma unroll
    for (int q = 0; q < 8; ++q) {
      float4 v = ip4[q];
      float4 wv = wv4[q];
      acc = fmaf(v.x, wv.x, acc);
      acc = fmaf(v.y, wv.y, acc);
      acc = fmaf(v.z, wv.z, acc);
      acc = fmaf(v.w, wv.w, acc);
    }
  }
  out[pix] = 1.0f / (1.0f + expf(-acc));
}

// ---------------------------------------------------------------------------
extern "C" void kernel_launch(void* const* d_in, const int* in_sizes, int n_in,
                              void* d_out, int out_size, void* d_ws,
                              size_t ws_size, hipStream_t stream) {
  const float* x    = (const float*)d_in[0];  // [1,1,400,512]
  const float* wdet = (const float*)d_in[1];  // [32,1,1,11]
  const float* bdet = (const float*)d_in[2];  // [32]
  const float* w1   = (const float*)d_in[3];  // [32,32,3,3]
  const float* b1   = (const float*)d_in[4];  // [32]
  const float* w2   = (const float*)d_in[5];  // [1,32,3,3]
  const float* b2   = (const float*)d_in[6];  // [1]
  float* out = (float*)d_out;                 // [1,1,256,256]

  float* ws = (float*)d_ws;
  __half* y2h = (__half*)ws;                         // [400][32][512] f16 = 13.1 MB
  float* vol  = ws + (A_ANG * CCH * DDET) / 2;       // [256][256][32] f32 = 8.4 MB
  float* sig1 = vol + NVOL * NVOL * CCH;             // [256][256][32] f32 = 8.4 MB

  k_detconv<<<dim3((A_ANG * CCH * DDET / 2) / 256), dim3(256), 0, stream>>>(
      x, wdet, bdet, y2h);
  // vol accumulated by 4 chunk-blocks per tile via line-coalesced atomics
  (void)hipMemsetAsync(vol, 0, (size_t)NVOL * NVOL * CCH * sizeof(float), stream);
  k_backproj<<<dim3(256 * NCHUNK), dim3(256), 0, stream>>>(y2h, vol);
  k_conv1<<<dim3(256 * 4), dim3(256), 0, stream>>>(vol, w1, b1, sig1);
  k_conv2<<<dim3(256), dim3(256), 0, stream>>>(sig1, w2, b2, out);
}